// Round 18
// baseline (88.942 us; speedup 1.0000x reference)
//
#include <hip/hip_runtime.h>

#define BATCH 64
#define NN 512
#define DIMS 8
#define RDIM 514          // NN + 2
#define WB 51             // |i-j| <= 51  (0.1 * 511 = 51.1)
#define NDIAG (2 * NN - 1)            // 1023 real diagonals
#define DPAD 1024                     // padded diag count (diag 1023 = INF)
#define CHUNK 64
#define NCHUNK 16                     // 16 * 64 = 1024 padded diagonals
#define GRP 16                        // checkpoint group size
#define NGRP 64                       // 1024 / 16

__device__ __forceinline__ constexpr int lo_of(int d) {
  int v = (d - (WB - 1)) >> 1;        // floor((d-50)/2)
  int w = d - (NN - 1);
  v = v > w ? v : w;
  return v > 0 ? v : 0;
}
__device__ __forceinline__ int hi_of(int d) {
  return min(min(d, NN - 1), (d + WB) >> 1);
}

// DPP wave shifts (VALU). bound_ctrl=false + old => shifted-in lanes get `old`.
// Semantics validated R4-R17 (kernels pass vs reference).
__device__ __forceinline__ float dpp_shr1(float x, float old) {  // lane i <- lane i-1
  return __int_as_float(__builtin_amdgcn_update_dpp(
      __float_as_int(old), __float_as_int(x), 0x138, 0xF, 0xF, false));
}
__device__ __forceinline__ float dpp_shl1(float x, float old) {  // lane i <- lane i+1
  return __int_as_float(__builtin_amdgcn_update_dpp(
      __float_as_int(old), __float_as_int(x), 0x130, 0xF, 0xF, false));
}

// ---------------------------------------------------------------------------
// Kernel 1: precompute banded D into Dws[b][n][lane], diag-major (R11 anchor).
// ---------------------------------------------------------------------------
__global__ __launch_bounds__(256) void dpre_kernel(const float* __restrict__ X,
                                                   const float* __restrict__ Y,
                                                   float* __restrict__ Dws) {
  const int w = blockIdx.x * 4 + (threadIdx.x >> 6);   // w in [0, BATCH*1024)
  const int lane = threadIdx.x & 63;
  const int b = w >> 10;
  const int n = w & 1023;
  const int lon = lo_of(n), hin = hi_of(n);
  const int i = lon + lane;
  const bool valid = (i <= hin) && (n < NDIAG);
  const int ic = min(i, NN - 1);
  const int jc = min(max(n - ic, 0), NN - 1);
  const float4* xp = (const float4*)(X + ((size_t)b * NN + ic) * DIMS);
  const float4* yp = (const float4*)(Y + ((size_t)b * NN + jc) * DIMS);
  float4 xa = xp[0], xb = xp[1];
  float4 ya = yp[0], yb = yp[1];
  float x2 = xa.x * xa.x + xa.y * xa.y + xa.z * xa.z + xa.w * xa.w +
             xb.x * xb.x + xb.y * xb.y + xb.z * xb.z + xb.w * xb.w;
  float y2 = ya.x * ya.x + ya.y * ya.y + ya.z * ya.z + ya.w * ya.w +
             yb.x * yb.x + yb.y * yb.y + yb.z * yb.z + yb.w * yb.w;
  float dot = xa.x * ya.x + xa.y * ya.y + xa.z * ya.z + xa.w * ya.w +
              xb.x * yb.x + xb.y * yb.y + xb.z * yb.z + xb.w * yb.w;
  float D = (x2 + y2) - 2.0f * dot;   // mirrors reference expansion
  Dws[((size_t)b * DPAD + n) * 64 + lane] = valid ? D : __builtin_inff();
}

// ---- shared recurrence step macros (R10-R17 proven semantics) --------------
#define BODY_STEP(qm, n)                                                    \
      const int lon = lo_of(n);                                             \
      const int d1 = lon - lo_of((n) - 1);                                  \
      const int d2 = lon - lo_of((n) - 2);                                  \
      float s_shl = dpp_shl1(r_d, INF);                                     \
      float s_shr = dpp_shr1(r_d, INF);                                     \
      float tt = d1 ? s_shl : s_shr;                                        \
      float vc = (d2 == 0) ? shm_shr : ((d2 == 1) ? r_dm1 : shm_shl);       \
      float r = (qm) + fminf(fminf(r_d, tt), vc);                           \
      r_dm1 = r_d; shm_shl = s_shl; shm_shr = s_shr; r_d = r;

// steady body (n in [52,972]): d2==1 -> vc=r_dm1; d1 = (n even) = (m even)
#define STEADY_STEP(qm, m)                                                  \
      float tt = ((m & 1) == 0) ? dpp_shl1(r_d, INF) : dpp_shr1(r_d, INF);  \
      float r = (qm) + fminf(fminf(r_d, tt), r_dm1);                        \
      r_dm1 = r_d; r_d = r;

// ---------------------------------------------------------------------------
// Kernel 2 (pass 1): serial chain, 1 wave/batch, launch_bounds(64,1), triple-
// buffered D prefetch (R12-proven). Checkpoints every 16 diagonals (R17).
// ---------------------------------------------------------------------------
__global__ __launch_bounds__(64, 1) void dtw_chain_kernel(const float* __restrict__ Dws,
                                                          float* __restrict__ ckpt,
                                                          float* __restrict__ out) {
  const int b = blockIdx.x;
  const int lane = threadIdx.x;
  const float INF = __builtin_inff();
  const float* __restrict__ Db = Dws + (size_t)b * DPAD * 64 + lane;
  float* __restrict__ ckb = ckpt + (size_t)b * (NGRP * 2) * 64 + lane;

  float qA[CHUNK], qB[CHUNK], qC[CHUNK];

#define LOAD_CHUNK(q, cRt)                                                  \
  { const float* _s = Db + (size_t)(cRt) * (CHUNK * 64);                    \
    _Pragma("unroll")                                                       \
    for (int m = 0; m < CHUNK; ++m) (q)[m] = _s[(size_t)m * 64]; }

#define CKPT16(g)                                                           \
  { ckb[(size_t)((g) * 2 + 0) * 64] = r_d;                                  \
    ckb[(size_t)((g) * 2 + 1) * 64] = r_dm1; }

  float r_d = INF, r_dm1 = INF, shm_shl = INF;
  float shm_shr = (lane == 0) ? 0.0f : INF;   // n=0 (d2==0) seed: rmin=0@lane0

  LOAD_CHUNK(qA, 0)
  LOAD_CHUNK(qB, 1)
  LOAD_CHUNK(qC, 2)
  {
#pragma unroll
    for (int m = 0; m < CHUNK; ++m) {
      if ((m & 15) == 0) { CKPT16(m >> 4) }
      BODY_STEP(qA[m], 0 + m)
    }
  }
  LOAD_CHUNK(qA, 3)
#pragma unroll 1
  for (int c = 1; c <= 10; c += 3) {        // chunks 1..12 (all steady)
    {
#pragma unroll
      for (int m = 0; m < CHUNK; ++m) {
        if ((m & 15) == 0) { CKPT16(c * 4 + (m >> 4)) }
        STEADY_STEP(qB[m], m)
      }
    }
    LOAD_CHUNK(qB, c + 3)
    {
#pragma unroll
      for (int m = 0; m < CHUNK; ++m) {
        if ((m & 15) == 0) { CKPT16((c + 1) * 4 + (m >> 4)) }
        STEADY_STEP(qC[m], m)
      }
    }
    LOAD_CHUNK(qC, c + 4)
    {
#pragma unroll
      for (int m = 0; m < CHUNK; ++m) {
        if ((m & 15) == 0) { CKPT16((c + 2) * 4 + (m >> 4)) }
        STEADY_STEP(qA[m], m)
      }
    }
    LOAD_CHUNK(qA, c + 5)
  }
  {
#pragma unroll
    for (int m = 0; m < CHUNK; ++m) {
      if ((m & 15) == 0) { CKPT16(13 * 4 + (m >> 4)) }
      STEADY_STEP(qB[m], m)
    }
  }
  {
#pragma unroll
    for (int m = 0; m < CHUNK; ++m) {
      if ((m & 15) == 0) { CKPT16(14 * 4 + (m >> 4)) }
      STEADY_STEP(qC[m], m)
    }
  }
  {
#pragma unroll
    for (int m = 0; m < CHUNK; ++m) {
      if ((m & 15) == 0) { CKPT16(15 * 4 + (m >> 4)) }
      BODY_STEP(qA[m], 960 + m)
    }
  }

  if (lane == 0) out[b] = r_dm1;    // lane0 of diag 1022 = R[511][511]
#undef LOAD_CHUNK
#undef CKPT16
}

// ---------------------------------------------------------------------------
// Kernel 3 (pass 2): ALL-WAVE-PARALLEL recompute + fused transpose (R17).
// ---------------------------------------------------------------------------
__global__ __launch_bounds__(256) void dtw_par_kernel(const float* __restrict__ Dws,
                                                      const float* __restrict__ ckpt,
                                                      float* __restrict__ out) {
  __shared__ float T[CHUNK][65];
  const int b = blockIdx.x >> 4;
  const int cc = blockIdx.x & 15;
  const int t = threadIdx.x;
  const int wave = t >> 6, lane = t & 63;
  const float INF = __builtin_inff();
  const int dlo = cc * CHUNK;

  float* __restrict__ Rfull = out + BATCH + (size_t)b * RDIM * RDIM;
  if (cc == 0 && t == 0) Rfull[0] = 0.0f;   // R[b][0][0] = 0

  // ---- parallel recompute: group g = cc*4 + wave, diags n0..n0+15 ----
  {
    const int g = cc * 4 + wave;
    const int n0 = g * GRP;
    const float* __restrict__ Db = Dws + ((size_t)b * DPAD + n0) * 64 + lane;
    float q[GRP];
#pragma unroll
    for (int m = 0; m < GRP; ++m) q[m] = Db[(size_t)m * 64];

    const float* __restrict__ ckb =
        ckpt + ((size_t)b * (NGRP * 2) + g * 2) * 64 + lane;
    float r_d = ckb[0];
    float r_dm1 = ckb[64];
    // group-entry invariant: shm_* == shifts of r_dm1 (group 0 re-seeds)
    float shm_shl = dpp_shl1(r_dm1, INF);
    float shm_shr = dpp_shr1(r_dm1, INF);
    if (g == 0) shm_shr = (lane == 0) ? 0.0f : INF;   // n=0 seed

    int lop = lo_of(n0 - 1), lopp = lo_of(n0 - 2);
#pragma unroll
    for (int m = 0; m < GRP; ++m) {
      const int n = n0 + m;
      const int lon = lo_of(n);
      const int d1 = lon - lop;
      const int d2 = lon - lopp;
      float s_shl = dpp_shl1(r_d, INF);
      float s_shr = dpp_shr1(r_d, INF);
      float tt = d1 ? s_shl : s_shr;
      float vc = (d2 == 0) ? shm_shr : ((d2 == 1) ? r_dm1 : shm_shl);
      float r = q[m] + fminf(fminf(r_d, tt), vc);
      T[wave * GRP + m][lane] = r;
      r_dm1 = r_d; shm_shl = s_shl; shm_shr = s_shr; r_d = r;
      lopp = lop; lop = lon;
    }
  }
  __syncthreads();

  // ---- row-major band segments (proven R6-R17 tail) ----
  const int dhi1 = min(dlo + CHUNK - 1, NDIAG - 1);
  const int rlo = lo_of(dlo);
  const int rhi = hi_of(dhi1);
  for (int i = rlo + wave; i <= rhi; i += 4) {
    const int j0 = max(max(i - WB, dlo - i), 0);
    const int j1 = min(min(i + WB, dhi1 - i), NN - 1);
    const int j = j0 + lane;
    if (j <= j1) {
      const int n = i + j;
      const int dd = n - dlo;
      const int l2 = i - lo_of(n);
      Rfull[(size_t)(i + 1) * RDIM + (j + 1)] = T[dd][l2];
    }
  }
}

// ---------------------------------------------------------------------------
// Fallback (ws too small): proven R3-style kernel (no workspace needed).
// ---------------------------------------------------------------------------
__global__ __launch_bounds__(256) void dtw_fb_kernel(const float* __restrict__ X,
                                                     const float* __restrict__ Y,
                                                     float* __restrict__ out) {
  __shared__ float xsT[DIMS][NN];
  __shared__ float ysT[DIMS][NN];
  __shared__ float x2s[NN];
  __shared__ float y2s[NN];
  __shared__ float ring[2][CHUNK][64];

  const int b = blockIdx.x;
  const int t = threadIdx.x;
  const float INF = __builtin_inff();

  {
    const float4* Xg = (const float4*)(X + (size_t)b * NN * DIMS);
    const float4* Yg = (const float4*)(Y + (size_t)b * NN * DIMS);
    for (int r = t; r < NN; r += 256) {
      float4 a0 = Xg[2 * r], a1 = Xg[2 * r + 1];
      xsT[0][r] = a0.x; xsT[1][r] = a0.y; xsT[2][r] = a0.z; xsT[3][r] = a0.w;
      xsT[4][r] = a1.x; xsT[5][r] = a1.y; xsT[6][r] = a1.z; xsT[7][r] = a1.w;
      x2s[r] = a0.x * a0.x + a0.y * a0.y + a0.z * a0.z + a0.w * a0.w +
               a1.x * a1.x + a1.y * a1.y + a1.z * a1.z + a1.w * a1.w;
      float4 c0 = Yg[2 * r], c1 = Yg[2 * r + 1];
      ysT[0][r] = c0.x; ysT[1][r] = c0.y; ysT[2][r] = c0.z; ysT[3][r] = c0.w;
      ysT[4][r] = c1.x; ysT[5][r] = c1.y; ysT[6][r] = c1.z; ysT[7][r] = c1.w;
      y2s[r] = c0.x * c0.x + c0.y * c0.y + c0.z * c0.z + c0.w * c0.w +
               c1.x * c1.x + c1.y * c1.y + c1.z * c1.z + c1.w * c1.w;
    }
  }
  __syncthreads();

  float* __restrict__ Rfull = out + BATCH + (size_t)b * RDIM * RDIM;
  if (t == 64) Rfull[0] = 0.0f;

  const int lane = t & 63;
  float r_d = INF, r_dm1 = INF;
  int lop = 0, lopp = 0;
  float Dcur = 0.0f;
  if (t < 64) {
    int i0 = min(lane, NN - 1);
    int j0 = max(0, min(0 - i0, NN - 1));
    float dot = xsT[0][i0] * ysT[0][j0] + xsT[1][i0] * ysT[1][j0] +
                xsT[2][i0] * ysT[2][j0] + xsT[3][i0] * ysT[3][j0] +
                xsT[4][i0] * ysT[4][j0] + xsT[5][i0] * ysT[5][j0] +
                xsT[6][i0] * ysT[6][j0] + xsT[7][i0] * ysT[7][j0];
    Dcur = (x2s[i0] + y2s[j0]) - 2.0f * dot;
  }

  for (int c = 0; c <= NCHUNK; ++c) {
    if (t < 64 && c < NCHUNK) {
      const int dlo = c * CHUNK;
      const int dhi = min(dlo + CHUNK, NDIAG);
      for (int n = dlo; n < dhi; ++n) {
        const int lon = lo_of(n), hin = hi_of(n);
        const int d1 = lon - lop;
        const int d2 = lon - lopp;
        const int sa = lane + d1;
        const int sb = sa - 1;
        const int sc = lane + d2 - 1;
        float va = __shfl(r_d, sa);   va = (sa < 64) ? va : INF;
        float vb = __shfl(r_d, sb);   vb = (sb >= 0) ? vb : INF;
        float vc = __shfl(r_dm1, sc); vc = (sc >= 0 && sc < 64) ? vc : INF;
        float rmin = fminf(fminf(vc, vb), va);
        if (n == 0) rmin = (lane == 0) ? 0.0f : INF;
        float r = Dcur + rmin;
        if (lane > hin - lon) r = INF;
        ring[c & 1][n - dlo][lane] = r;
        const int lon1 = lo_of(n + 1);
        int ii = min(lon1 + lane, NN - 1);
        int jj = n + 1 - ii; jj = max(0, min(jj, NN - 1));
        float dot = xsT[0][ii] * ysT[0][jj] + xsT[1][ii] * ysT[1][jj] +
                    xsT[2][ii] * ysT[2][jj] + xsT[3][ii] * ysT[3][jj] +
                    xsT[4][ii] * ysT[4][jj] + xsT[5][ii] * ysT[5][jj] +
                    xsT[6][ii] * ysT[6][jj] + xsT[7][ii] * ysT[7][jj];
        Dcur = (x2s[ii] + y2s[jj]) - 2.0f * dot;
        r_dm1 = r_d; r_d = r;
        lopp = lop; lop = lon;
      }
    } else if (t >= 64 && c >= 1) {
      const int dlo = (c - 1) * CHUNK;
      const int dhi = min(dlo + CHUNK, NDIAG);
      const int nslots = (dhi - dlo) * 64;
      const int buf = (c - 1) & 1;
      for (int s = t - 64; s < nslots; s += 192) {
        const int dd = s >> 6, l2 = s & 63;
        const int n = dlo + dd;
        const int lon = lo_of(n);
        const int i = lon + l2;
        if (i <= hi_of(n)) {
          Rfull[(size_t)(i + 1) * RDIM + (n - i + 1)] = ring[buf][dd][l2];
        }
      }
    }
    __syncthreads();
  }

  if (t == 0) out[b] = r_d;
}

extern "C" void kernel_launch(void* const* d_in, const int* in_sizes, int n_in,
                              void* d_out, int out_size, void* d_ws, size_t ws_size,
                              hipStream_t stream) {
  const float* X = (const float*)d_in[0];
  const float* Y = (const float*)d_in[1];
  float* out = (float*)d_out;

  const size_t nD = (size_t)BATCH * DPAD * 64;            // Dws floats (16.78 MB)
  const size_t nC = (size_t)BATCH * NGRP * 2 * 64;        // ckpt floats (2 MB)
  if (ws_size >= (nD + nC) * sizeof(float)) {
    float* Dws = (float*)d_ws;
    float* ckpt = (float*)d_ws + nD;
    // DIAGNOSTIC (this round only): dpre x2, par x3 — all idempotent, so the
    // graph stays deterministic and outputs are identical.
    //   dur_R18 - dur_R17 = dpre + 2*par + 3*boundary
    // Combined with dur_R17 = dpre + chain + par + 2*boundary and chain ~ 9
    // (R12 measurement), this solves the full per-kernel split.
    dpre_kernel<<<(BATCH * DPAD) / 4, 256, 0, stream>>>(X, Y, Dws);
    dpre_kernel<<<(BATCH * DPAD) / 4, 256, 0, stream>>>(X, Y, Dws);
    dtw_chain_kernel<<<BATCH, 64, 0, stream>>>(Dws, ckpt, out);
    dtw_par_kernel<<<BATCH * NCHUNK, 256, 0, stream>>>(Dws, ckpt, out);
    dtw_par_kernel<<<BATCH * NCHUNK, 256, 0, stream>>>(Dws, ckpt, out);
    dtw_par_kernel<<<BATCH * NCHUNK, 256, 0, stream>>>(Dws, ckpt, out);
  } else {
    dtw_fb_kernel<<<BATCH, 256, 0, stream>>>(X, Y, out);
  }
}

// Round 19
// 50.785 us; speedup vs baseline: 1.7514x; 1.7514x over previous
//
#include <hip/hip_runtime.h>

#define BATCH 64
#define NN 512
#define DIMS 8
#define RDIM 514          // NN + 2
#define WB 51             // |i-j| <= 51  (0.1 * 511 = 51.1)
#define NDIAG (2 * NN - 1)            // 1023 real diagonals
#define DPAD 1024                     // padded diag count (diag 1023 = INF)
#define CHUNK 64
#define NCHUNK 16                     // 16 * 64 = 1024 padded diagonals
#define GRP 16                        // checkpoint group size
#define NGRP 64                       // 1024 / 16

__device__ __forceinline__ constexpr int lo_of(int d) {
  int v = (d - (WB - 1)) >> 1;        // floor((d-50)/2)
  int w = d - (NN - 1);
  v = v > w ? v : w;
  return v > 0 ? v : 0;
}
__device__ __forceinline__ int hi_of(int d) {
  return min(min(d, NN - 1), (d + WB) >> 1);
}

// DPP wave shifts (VALU). bound_ctrl=false + old => shifted-in lanes get `old`.
// Semantics validated R4-R18 (kernels pass vs reference).
__device__ __forceinline__ float dpp_shr1(float x, float old) {  // lane i <- lane i-1
  return __int_as_float(__builtin_amdgcn_update_dpp(
      __float_as_int(old), __float_as_int(x), 0x138, 0xF, 0xF, false));
}
__device__ __forceinline__ float dpp_shl1(float x, float old) {  // lane i <- lane i+1
  return __int_as_float(__builtin_amdgcn_update_dpp(
      __float_as_int(old), __float_as_int(x), 0x130, 0xF, 0xF, false));
}

// ---------------------------------------------------------------------------
// Kernel 1: precompute banded D into Dws[b][n][lane], diag-major (R11 anchor,
// UNCHANGED).
// ---------------------------------------------------------------------------
__global__ __launch_bounds__(256) void dpre_kernel(const float* __restrict__ X,
                                                   const float* __restrict__ Y,
                                                   float* __restrict__ Dws) {
  const int w = blockIdx.x * 4 + (threadIdx.x >> 6);   // w in [0, BATCH*1024)
  const int lane = threadIdx.x & 63;
  const int b = w >> 10;
  const int n = w & 1023;
  const int lon = lo_of(n), hin = hi_of(n);
  const int i = lon + lane;
  const bool valid = (i <= hin) && (n < NDIAG);
  const int ic = min(i, NN - 1);
  const int jc = min(max(n - ic, 0), NN - 1);
  const float4* xp = (const float4*)(X + ((size_t)b * NN + ic) * DIMS);
  const float4* yp = (const float4*)(Y + ((size_t)b * NN + jc) * DIMS);
  float4 xa = xp[0], xb = xp[1];
  float4 ya = yp[0], yb = yp[1];
  float x2 = xa.x * xa.x + xa.y * xa.y + xa.z * xa.z + xa.w * xa.w +
             xb.x * xb.x + xb.y * xb.y + xb.z * xb.z + xb.w * xb.w;
  float y2 = ya.x * ya.x + ya.y * ya.y + ya.z * ya.z + ya.w * ya.w +
             yb.x * yb.x + yb.y * yb.y + yb.z * yb.z + yb.w * yb.w;
  float dot = xa.x * ya.x + xa.y * ya.y + xa.z * ya.z + xa.w * ya.w +
              xb.x * yb.x + xb.y * yb.y + xb.z * yb.z + xb.w * yb.w;
  float D = (x2 + y2) - 2.0f * dot;   // mirrors reference expansion
  Dws[((size_t)b * DPAD + n) * 64 + lane] = valid ? D : __builtin_inff();
}

// ---- shared recurrence step macros (R10-R18 proven semantics) --------------
#define BODY_STEP(qm, n)                                                    \
      const int lon = lo_of(n);                                             \
      const int d1 = lon - lo_of((n) - 1);                                  \
      const int d2 = lon - lo_of((n) - 2);                                  \
      float s_shl = dpp_shl1(r_d, INF);                                     \
      float s_shr = dpp_shr1(r_d, INF);                                     \
      float tt = d1 ? s_shl : s_shr;                                        \
      float vc = (d2 == 0) ? shm_shr : ((d2 == 1) ? r_dm1 : shm_shl);       \
      float r = (qm) + fminf(fminf(r_d, tt), vc);                           \
      r_dm1 = r_d; shm_shl = s_shl; shm_shr = s_shr; r_d = r;

// steady body (n in [52,972]): d2==1 -> vc=r_dm1; d1 = (n even) = (m even)
#define STEADY_STEP(qm, m)                                                  \
      float tt = ((m & 1) == 0) ? dpp_shl1(r_d, INF) : dpp_shr1(r_d, INF);  \
      float r = (qm) + fminf(fminf(r_d, tt), r_dm1);                        \
      r_dm1 = r_d; r_d = r;

// ---------------------------------------------------------------------------
// Kernel 2 (pass 1): serial chain, 1 wave/batch, launch_bounds(64,1), triple-
// buffered D prefetch (R12-proven). CHANGE vs R17: checkpoints go to LDS
// (ds_write -> lgkmcnt, completes in tens of cycles) instead of global
// (global_store -> shares the in-order vmcnt counter with the q-loads, forcing
// ~300-600cyc store drains onto the critical chain — the R17/R18-diagnosed
// ~2x chain regression). One float4 LDS->global flush at kernel end.
// ---------------------------------------------------------------------------
__global__ __launch_bounds__(64, 1) void dtw_chain_kernel(const float* __restrict__ Dws,
                                                          float* __restrict__ ckpt,
                                                          float* __restrict__ out) {
  __shared__ float ckls[NGRP * 2 * 64];   // 32 KB checkpoint staging
  const int b = blockIdx.x;
  const int lane = threadIdx.x;
  const float INF = __builtin_inff();
  const float* __restrict__ Db = Dws + (size_t)b * DPAD * 64 + lane;

  float qA[CHUNK], qB[CHUNK], qC[CHUNK];

#define LOAD_CHUNK(q, cRt)                                                  \
  { const float* _s = Db + (size_t)(cRt) * (CHUNK * 64);                    \
    _Pragma("unroll")                                                       \
    for (int m = 0; m < CHUNK; ++m) (q)[m] = _s[(size_t)m * 64]; }

// checkpoint at entry of group g — LDS, fire-and-forget on lgkmcnt
#define CKPT16(g)                                                           \
  { ckls[((g) * 2 + 0) * 64 + lane] = r_d;                                  \
    ckls[((g) * 2 + 1) * 64 + lane] = r_dm1; }

  float r_d = INF, r_dm1 = INF, shm_shl = INF;
  float shm_shr = (lane == 0) ? 0.0f : INF;   // n=0 (d2==0) seed: rmin=0@lane0

  LOAD_CHUNK(qA, 0)
  LOAD_CHUNK(qB, 1)
  LOAD_CHUNK(qC, 2)
  {
#pragma unroll
    for (int m = 0; m < CHUNK; ++m) {
      if ((m & 15) == 0) { CKPT16(m >> 4) }
      BODY_STEP(qA[m], 0 + m)
    }
  }
  LOAD_CHUNK(qA, 3)
#pragma unroll 1
  for (int c = 1; c <= 10; c += 3) {        // chunks 1..12 (all steady)
    {
#pragma unroll
      for (int m = 0; m < CHUNK; ++m) {
        if ((m & 15) == 0) { CKPT16(c * 4 + (m >> 4)) }
        STEADY_STEP(qB[m], m)
      }
    }
    LOAD_CHUNK(qB, c + 3)
    {
#pragma unroll
      for (int m = 0; m < CHUNK; ++m) {
        if ((m & 15) == 0) { CKPT16((c + 1) * 4 + (m >> 4)) }
        STEADY_STEP(qC[m], m)
      }
    }
    LOAD_CHUNK(qC, c + 4)
    {
#pragma unroll
      for (int m = 0; m < CHUNK; ++m) {
        if ((m & 15) == 0) { CKPT16((c + 2) * 4 + (m >> 4)) }
        STEADY_STEP(qA[m], m)
      }
    }
    LOAD_CHUNK(qA, c + 5)
  }
  {
#pragma unroll
    for (int m = 0; m < CHUNK; ++m) {
      if ((m & 15) == 0) { CKPT16(13 * 4 + (m >> 4)) }
      STEADY_STEP(qB[m], m)
    }
  }
  {
#pragma unroll
    for (int m = 0; m < CHUNK; ++m) {
      if ((m & 15) == 0) { CKPT16(14 * 4 + (m >> 4)) }
      STEADY_STEP(qC[m], m)
    }
  }
  {
#pragma unroll
    for (int m = 0; m < CHUNK; ++m) {
      if ((m & 15) == 0) { CKPT16(15 * 4 + (m >> 4)) }
      BODY_STEP(qA[m], 960 + m)
    }
  }

  if (lane == 0) out[b] = r_dm1;    // lane0 of diag 1022 = R[511][511]

  // ---- flush LDS ckpt -> global (2048 float4s, coalesced, ~1 us) ----
  {
    const float4* s4 = (const float4*)ckls;
    float4* d4 = (float4*)(ckpt + (size_t)b * (NGRP * 2) * 64);
    for (int k = lane; k < NGRP * 2 * 16; k += 64) d4[k] = s4[k];
  }
#undef LOAD_CHUNK
#undef CKPT16
}

// ---------------------------------------------------------------------------
// Kernel 3 (pass 2): ALL-WAVE-PARALLEL recompute + fused transpose (R17,
// UNCHANGED).
// ---------------------------------------------------------------------------
__global__ __launch_bounds__(256) void dtw_par_kernel(const float* __restrict__ Dws,
                                                      const float* __restrict__ ckpt,
                                                      float* __restrict__ out) {
  __shared__ float T[CHUNK][65];
  const int b = blockIdx.x >> 4;
  const int cc = blockIdx.x & 15;
  const int t = threadIdx.x;
  const int wave = t >> 6, lane = t & 63;
  const float INF = __builtin_inff();
  const int dlo = cc * CHUNK;

  float* __restrict__ Rfull = out + BATCH + (size_t)b * RDIM * RDIM;
  if (cc == 0 && t == 0) Rfull[0] = 0.0f;   // R[b][0][0] = 0

  // ---- parallel recompute: group g = cc*4 + wave, diags n0..n0+15 ----
  {
    const int g = cc * 4 + wave;
    const int n0 = g * GRP;
    const float* __restrict__ Db = Dws + ((size_t)b * DPAD + n0) * 64 + lane;
    float q[GRP];
#pragma unroll
    for (int m = 0; m < GRP; ++m) q[m] = Db[(size_t)m * 64];

    const float* __restrict__ ckb =
        ckpt + ((size_t)b * (NGRP * 2) + g * 2) * 64 + lane;
    float r_d = ckb[0];
    float r_dm1 = ckb[64];
    // group-entry invariant: shm_* == shifts of r_dm1 (group 0 re-seeds)
    float shm_shl = dpp_shl1(r_dm1, INF);
    float shm_shr = dpp_shr1(r_dm1, INF);
    if (g == 0) shm_shr = (lane == 0) ? 0.0f : INF;   // n=0 seed

    int lop = lo_of(n0 - 1), lopp = lo_of(n0 - 2);
#pragma unroll
    for (int m = 0; m < GRP; ++m) {
      const int n = n0 + m;
      const int lon = lo_of(n);
      const int d1 = lon - lop;
      const int d2 = lon - lopp;
      float s_shl = dpp_shl1(r_d, INF);
      float s_shr = dpp_shr1(r_d, INF);
      float tt = d1 ? s_shl : s_shr;
      float vc = (d2 == 0) ? shm_shr : ((d2 == 1) ? r_dm1 : shm_shl);
      float r = q[m] + fminf(fminf(r_d, tt), vc);
      T[wave * GRP + m][lane] = r;
      r_dm1 = r_d; shm_shl = s_shl; shm_shr = s_shr; r_d = r;
      lopp = lop; lop = lon;
    }
  }
  __syncthreads();

  // ---- row-major band segments (proven R6-R18 tail) ----
  const int dhi1 = min(dlo + CHUNK - 1, NDIAG - 1);
  const int rlo = lo_of(dlo);
  const int rhi = hi_of(dhi1);
  for (int i = rlo + wave; i <= rhi; i += 4) {
    const int j0 = max(max(i - WB, dlo - i), 0);
    const int j1 = min(min(i + WB, dhi1 - i), NN - 1);
    const int j = j0 + lane;
    if (j <= j1) {
      const int n = i + j;
      const int dd = n - dlo;
      const int l2 = i - lo_of(n);
      Rfull[(size_t)(i + 1) * RDIM + (j + 1)] = T[dd][l2];
    }
  }
}

// ---------------------------------------------------------------------------
// Fallback (ws too small): proven R3-style kernel (no workspace needed).
// ---------------------------------------------------------------------------
__global__ __launch_bounds__(256) void dtw_fb_kernel(const float* __restrict__ X,
                                                     const float* __restrict__ Y,
                                                     float* __restrict__ out) {
  __shared__ float xsT[DIMS][NN];
  __shared__ float ysT[DIMS][NN];
  __shared__ float x2s[NN];
  __shared__ float y2s[NN];
  __shared__ float ring[2][CHUNK][64];

  const int b = blockIdx.x;
  const int t = threadIdx.x;
  const float INF = __builtin_inff();

  {
    const float4* Xg = (const float4*)(X + (size_t)b * NN * DIMS);
    const float4* Yg = (const float4*)(Y + (size_t)b * NN * DIMS);
    for (int r = t; r < NN; r += 256) {
      float4 a0 = Xg[2 * r], a1 = Xg[2 * r + 1];
      xsT[0][r] = a0.x; xsT[1][r] = a0.y; xsT[2][r] = a0.z; xsT[3][r] = a0.w;
      xsT[4][r] = a1.x; xsT[5][r] = a1.y; xsT[6][r] = a1.z; xsT[7][r] = a1.w;
      x2s[r] = a0.x * a0.x + a0.y * a0.y + a0.z * a0.z + a0.w * a0.w +
               a1.x * a1.x + a1.y * a1.y + a1.z * a1.z + a1.w * a1.w;
      float4 c0 = Yg[2 * r], c1 = Yg[2 * r + 1];
      ysT[0][r] = c0.x; ysT[1][r] = c0.y; ysT[2][r] = c0.z; ysT[3][r] = c0.w;
      ysT[4][r] = c1.x; ysT[5][r] = c1.y; ysT[6][r] = c1.z; ysT[7][r] = c1.w;
      y2s[r] = c0.x * c0.x + c0.y * c0.y + c0.z * c0.z + c0.w * c0.w +
               c1.x * c1.x + c1.y * c1.y + c1.z * c1.z + c1.w * c1.w;
    }
  }
  __syncthreads();

  float* __restrict__ Rfull = out + BATCH + (size_t)b * RDIM * RDIM;
  if (t == 64) Rfull[0] = 0.0f;

  const int lane = t & 63;
  float r_d = INF, r_dm1 = INF;
  int lop = 0, lopp = 0;
  float Dcur = 0.0f;
  if (t < 64) {
    int i0 = min(lane, NN - 1);
    int j0 = max(0, min(0 - i0, NN - 1));
    float dot = xsT[0][i0] * ysT[0][j0] + xsT[1][i0] * ysT[1][j0] +
                xsT[2][i0] * ysT[2][j0] + xsT[3][i0] * ysT[3][j0] +
                xsT[4][i0] * ysT[4][j0] + xsT[5][i0] * ysT[5][j0] +
                xsT[6][i0] * ysT[6][j0] + xsT[7][i0] * ysT[7][j0];
    Dcur = (x2s[i0] + y2s[j0]) - 2.0f * dot;
  }

  for (int c = 0; c <= NCHUNK; ++c) {
    if (t < 64 && c < NCHUNK) {
      const int dlo = c * CHUNK;
      const int dhi = min(dlo + CHUNK, NDIAG);
      for (int n = dlo; n < dhi; ++n) {
        const int lon = lo_of(n), hin = hi_of(n);
        const int d1 = lon - lop;
        const int d2 = lon - lopp;
        const int sa = lane + d1;
        const int sb = sa - 1;
        const int sc = lane + d2 - 1;
        float va = __shfl(r_d, sa);   va = (sa < 64) ? va : INF;
        float vb = __shfl(r_d, sb);   vb = (sb >= 0) ? vb : INF;
        float vc = __shfl(r_dm1, sc); vc = (sc >= 0 && sc < 64) ? vc : INF;
        float rmin = fminf(fminf(vc, vb), va);
        if (n == 0) rmin = (lane == 0) ? 0.0f : INF;
        float r = Dcur + rmin;
        if (lane > hin - lon) r = INF;
        ring[c & 1][n - dlo][lane] = r;
        const int lon1 = lo_of(n + 1);
        int ii = min(lon1 + lane, NN - 1);
        int jj = n + 1 - ii; jj = max(0, min(jj, NN - 1));
        float dot = xsT[0][ii] * ysT[0][jj] + xsT[1][ii] * ysT[1][jj] +
                    xsT[2][ii] * ysT[2][jj] + xsT[3][ii] * ysT[3][jj] +
                    xsT[4][ii] * ysT[4][jj] + xsT[5][ii] * ysT[5][jj] +
                    xsT[6][ii] * ysT[6][jj] + xsT[7][ii] * ysT[7][jj];
        Dcur = (x2s[ii] + y2s[jj]) - 2.0f * dot;
        r_dm1 = r_d; r_d = r;
        lopp = lop; lop = lon;
      }
    } else if (t >= 64 && c >= 1) {
      const int dlo = (c - 1) * CHUNK;
      const int dhi = min(dlo + CHUNK, NDIAG);
      const int nslots = (dhi - dlo) * 64;
      const int buf = (c - 1) & 1;
      for (int s = t - 64; s < nslots; s += 192) {
        const int dd = s >> 6, l2 = s & 63;
        const int n = dlo + dd;
        const int lon = lo_of(n);
        const int i = lon + l2;
        if (i <= hi_of(n)) {
          Rfull[(size_t)(i + 1) * RDIM + (n - i + 1)] = ring[buf][dd][l2];
        }
      }
    }
    __syncthreads();
  }

  if (t == 0) out[b] = r_d;
}

extern "C" void kernel_launch(void* const* d_in, const int* in_sizes, int n_in,
                              void* d_out, int out_size, void* d_ws, size_t ws_size,
                              hipStream_t stream) {
  const float* X = (const float*)d_in[0];
  const float* Y = (const float*)d_in[1];
  float* out = (float*)d_out;

  const size_t nD = (size_t)BATCH * DPAD * 64;            // Dws floats (16.78 MB)
  const size_t nC = (size_t)BATCH * NGRP * 2 * 64;        // ckpt floats (2 MB)
  if (ws_size >= (nD + nC) * sizeof(float)) {
    float* Dws = (float*)d_ws;
    float* ckpt = (float*)d_ws + nD;
    dpre_kernel<<<(BATCH * DPAD) / 4, 256, 0, stream>>>(X, Y, Dws);
    dtw_chain_kernel<<<BATCH, 64, 0, stream>>>(Dws, ckpt, out);
    dtw_par_kernel<<<BATCH * NCHUNK, 256, 0, stream>>>(Dws, ckpt, out);
  } else {
    dtw_fb_kernel<<<BATCH, 256, 0, stream>>>(X, Y, out);
  }
}

// Round 20
// 48.509 us; speedup vs baseline: 1.8335x; 1.0469x over previous
//
#include <hip/hip_runtime.h>

#define BATCH 64
#define NN 512
#define DIMS 8
#define RDIM 514          // NN + 2
#define WB 51             // |i-j| <= 51  (0.1 * 511 = 51.1)
#define NDIAG (2 * NN - 1)            // 1023 real diagonals
#define DPAD 1024                     // padded diag count (diag 1023 = INF)
#define CHUNK 64
#define NCHUNK 16                     // 16 * 64 = 1024 padded diagonals
#define GRP 16                        // checkpoint group size
#define NGRP 64                       // 1024 / 16

__device__ __forceinline__ constexpr int lo_of(int d) {
  int v = (d - (WB - 1)) >> 1;        // floor((d-50)/2)
  int w = d - (NN - 1);
  v = v > w ? v : w;
  return v > 0 ? v : 0;
}
__device__ __forceinline__ int hi_of(int d) {
  return min(min(d, NN - 1), (d + WB) >> 1);
}

// DPP wave shifts (VALU). bound_ctrl=false + old => shifted-in lanes get `old`.
// Semantics validated R4-R19 (kernels pass vs reference).
__device__ __forceinline__ float dpp_shr1(float x, float old) {  // lane i <- lane i-1
  return __int_as_float(__builtin_amdgcn_update_dpp(
      __float_as_int(old), __float_as_int(x), 0x138, 0xF, 0xF, false));
}
__device__ __forceinline__ float dpp_shl1(float x, float old) {  // lane i <- lane i+1
  return __int_as_float(__builtin_amdgcn_update_dpp(
      __float_as_int(old), __float_as_int(x), 0x130, 0xF, 0xF, false));
}

// ---------------------------------------------------------------------------
// Kernel 1: precompute banded D into Dws[b][n][lane], diag-major.
// XCD-LOCALITY REMAP (R20): block i handles batch b = i % 64 -> lands on
// XCD i%8 == b%8, the SAME XCD as batch b's chain/par blocks. All Dws[b]
// traffic (262 KB/batch, 2.1 MB/XCD) then stays in that XCD's 4MB L2
// instead of crossing the non-coherent per-XCD L2s via L3/HBM.
// ---------------------------------------------------------------------------
__global__ __launch_bounds__(256) void dpre_kernel(const float* __restrict__ X,
                                                   const float* __restrict__ Y,
                                                   float* __restrict__ Dws) {
  const int b = blockIdx.x & 63;                       // batch (== XCD class)
  const int n = (blockIdx.x >> 6) * 4 + (threadIdx.x >> 6);  // diag in [0,1024)
  const int lane = threadIdx.x & 63;
  const int lon = lo_of(n), hin = hi_of(n);
  const int i = lon + lane;
  const bool valid = (i <= hin) && (n < NDIAG);
  const int ic = min(i, NN - 1);
  const int jc = min(max(n - ic, 0), NN - 1);
  const float4* xp = (const float4*)(X + ((size_t)b * NN + ic) * DIMS);
  const float4* yp = (const float4*)(Y + ((size_t)b * NN + jc) * DIMS);
  float4 xa = xp[0], xb = xp[1];
  float4 ya = yp[0], yb = yp[1];
  float x2 = xa.x * xa.x + xa.y * xa.y + xa.z * xa.z + xa.w * xa.w +
             xb.x * xb.x + xb.y * xb.y + xb.z * xb.z + xb.w * xb.w;
  float y2 = ya.x * ya.x + ya.y * ya.y + ya.z * ya.z + ya.w * ya.w +
             yb.x * yb.x + yb.y * yb.y + yb.z * yb.z + yb.w * yb.w;
  float dot = xa.x * ya.x + xa.y * ya.y + xa.z * ya.z + xa.w * ya.w +
              xb.x * yb.x + xb.y * yb.y + xb.z * yb.z + xb.w * yb.w;
  float D = (x2 + y2) - 2.0f * dot;   // mirrors reference expansion
  Dws[((size_t)b * DPAD + n) * 64 + lane] = valid ? D : __builtin_inff();
}

// ---- shared recurrence step macros (R10-R19 proven semantics) --------------
#define BODY_STEP(qm, n)                                                    \
      const int lon = lo_of(n);                                             \
      const int d1 = lon - lo_of((n) - 1);                                  \
      const int d2 = lon - lo_of((n) - 2);                                  \
      float s_shl = dpp_shl1(r_d, INF);                                     \
      float s_shr = dpp_shr1(r_d, INF);                                     \
      float tt = d1 ? s_shl : s_shr;                                        \
      float vc = (d2 == 0) ? shm_shr : ((d2 == 1) ? r_dm1 : shm_shl);       \
      float r = (qm) + fminf(fminf(r_d, tt), vc);                           \
      r_dm1 = r_d; shm_shl = s_shl; shm_shr = s_shr; r_d = r;

// steady body (n in [52,972]): d2==1 -> vc=r_dm1; d1 = (n even) = (m even)
#define STEADY_STEP(qm, m)                                                  \
      float tt = ((m & 1) == 0) ? dpp_shl1(r_d, INF) : dpp_shr1(r_d, INF);  \
      float r = (qm) + fminf(fminf(r_d, tt), r_dm1);                        \
      r_dm1 = r_d; r_d = r;

// ---------------------------------------------------------------------------
// Kernel 2 (pass 1): serial chain, 1 wave/batch, launch_bounds(64,1), triple-
// buffered D prefetch (R12-proven). LDS checkpoints (R19). Block b -> XCD b%8;
// with the R20 remap its Dws[b] reads are now L2-LOCAL (was: cross-XCD cold).
// ---------------------------------------------------------------------------
__global__ __launch_bounds__(64, 1) void dtw_chain_kernel(const float* __restrict__ Dws,
                                                          float* __restrict__ ckpt,
                                                          float* __restrict__ out) {
  __shared__ float ckls[NGRP * 2 * 64];   // 32 KB checkpoint staging
  const int b = blockIdx.x;
  const int lane = threadIdx.x;
  const float INF = __builtin_inff();
  const float* __restrict__ Db = Dws + (size_t)b * DPAD * 64 + lane;

  float qA[CHUNK], qB[CHUNK], qC[CHUNK];

#define LOAD_CHUNK(q, cRt)                                                  \
  { const float* _s = Db + (size_t)(cRt) * (CHUNK * 64);                    \
    _Pragma("unroll")                                                       \
    for (int m = 0; m < CHUNK; ++m) (q)[m] = _s[(size_t)m * 64]; }

#define CKPT16(g)                                                           \
  { ckls[((g) * 2 + 0) * 64 + lane] = r_d;                                  \
    ckls[((g) * 2 + 1) * 64 + lane] = r_dm1; }

  float r_d = INF, r_dm1 = INF, shm_shl = INF;
  float shm_shr = (lane == 0) ? 0.0f : INF;   // n=0 (d2==0) seed: rmin=0@lane0

  LOAD_CHUNK(qA, 0)
  LOAD_CHUNK(qB, 1)
  LOAD_CHUNK(qC, 2)
  {
#pragma unroll
    for (int m = 0; m < CHUNK; ++m) {
      if ((m & 15) == 0) { CKPT16(m >> 4) }
      BODY_STEP(qA[m], 0 + m)
    }
  }
  LOAD_CHUNK(qA, 3)
#pragma unroll 1
  for (int c = 1; c <= 10; c += 3) {        // chunks 1..12 (all steady)
    {
#pragma unroll
      for (int m = 0; m < CHUNK; ++m) {
        if ((m & 15) == 0) { CKPT16(c * 4 + (m >> 4)) }
        STEADY_STEP(qB[m], m)
      }
    }
    LOAD_CHUNK(qB, c + 3)
    {
#pragma unroll
      for (int m = 0; m < CHUNK; ++m) {
        if ((m & 15) == 0) { CKPT16((c + 1) * 4 + (m >> 4)) }
        STEADY_STEP(qC[m], m)
      }
    }
    LOAD_CHUNK(qC, c + 4)
    {
#pragma unroll
      for (int m = 0; m < CHUNK; ++m) {
        if ((m & 15) == 0) { CKPT16((c + 2) * 4 + (m >> 4)) }
        STEADY_STEP(qA[m], m)
      }
    }
    LOAD_CHUNK(qA, c + 5)
  }
  {
#pragma unroll
    for (int m = 0; m < CHUNK; ++m) {
      if ((m & 15) == 0) { CKPT16(13 * 4 + (m >> 4)) }
      STEADY_STEP(qB[m], m)
    }
  }
  {
#pragma unroll
    for (int m = 0; m < CHUNK; ++m) {
      if ((m & 15) == 0) { CKPT16(14 * 4 + (m >> 4)) }
      STEADY_STEP(qC[m], m)
    }
  }
  {
#pragma unroll
    for (int m = 0; m < CHUNK; ++m) {
      if ((m & 15) == 0) { CKPT16(15 * 4 + (m >> 4)) }
      BODY_STEP(qA[m], 960 + m)
    }
  }

  if (lane == 0) out[b] = r_dm1;    // lane0 of diag 1022 = R[511][511]

  // ---- flush LDS ckpt -> global (coalesced float4, L2-local) ----
  {
    const float4* s4 = (const float4*)ckls;
    float4* d4 = (float4*)(ckpt + (size_t)b * (NGRP * 2) * 64);
    for (int k = lane; k < NGRP * 2 * 16; k += 64) d4[k] = s4[k];
  }
#undef LOAD_CHUNK
#undef CKPT16
}

// ---------------------------------------------------------------------------
// Kernel 3 (pass 2): ALL-WAVE-PARALLEL recompute + fused transpose (R17).
// XCD-LOCALITY REMAP (R20): block j -> batch b = j % 64, chunk cc = j / 64,
// so XCD j%8 == b%8 and Dws[b]/ckpt[b] reads hit the local L2.
// ---------------------------------------------------------------------------
__global__ __launch_bounds__(256) void dtw_par_kernel(const float* __restrict__ Dws,
                                                      const float* __restrict__ ckpt,
                                                      float* __restrict__ out) {
  __shared__ float T[CHUNK][65];
  const int b = blockIdx.x & 63;
  const int cc = blockIdx.x >> 6;
  const int t = threadIdx.x;
  const int wave = t >> 6, lane = t & 63;
  const float INF = __builtin_inff();
  const int dlo = cc * CHUNK;

  float* __restrict__ Rfull = out + BATCH + (size_t)b * RDIM * RDIM;
  if (cc == 0 && t == 0) Rfull[0] = 0.0f;   // R[b][0][0] = 0

  // ---- parallel recompute: group g = cc*4 + wave, diags n0..n0+15 ----
  {
    const int g = cc * 4 + wave;
    const int n0 = g * GRP;
    const float* __restrict__ Db = Dws + ((size_t)b * DPAD + n0) * 64 + lane;
    float q[GRP];
#pragma unroll
    for (int m = 0; m < GRP; ++m) q[m] = Db[(size_t)m * 64];

    const float* __restrict__ ckb =
        ckpt + ((size_t)b * (NGRP * 2) + g * 2) * 64 + lane;
    float r_d = ckb[0];
    float r_dm1 = ckb[64];
    // group-entry invariant: shm_* == shifts of r_dm1 (group 0 re-seeds)
    float shm_shl = dpp_shl1(r_dm1, INF);
    float shm_shr = dpp_shr1(r_dm1, INF);
    if (g == 0) shm_shr = (lane == 0) ? 0.0f : INF;   // n=0 seed

    int lop = lo_of(n0 - 1), lopp = lo_of(n0 - 2);
#pragma unroll
    for (int m = 0; m < GRP; ++m) {
      const int n = n0 + m;
      const int lon = lo_of(n);
      const int d1 = lon - lop;
      const int d2 = lon - lopp;
      float s_shl = dpp_shl1(r_d, INF);
      float s_shr = dpp_shr1(r_d, INF);
      float tt = d1 ? s_shl : s_shr;
      float vc = (d2 == 0) ? shm_shr : ((d2 == 1) ? r_dm1 : shm_shl);
      float r = q[m] + fminf(fminf(r_d, tt), vc);
      T[wave * GRP + m][lane] = r;
      r_dm1 = r_d; shm_shl = s_shl; shm_shr = s_shr; r_d = r;
      lopp = lop; lop = lon;
    }
  }
  __syncthreads();

  // ---- row-major band segments (proven R6-R19 tail) ----
  const int dhi1 = min(dlo + CHUNK - 1, NDIAG - 1);
  const int rlo = lo_of(dlo);
  const int rhi = hi_of(dhi1);
  for (int i = rlo + wave; i <= rhi; i += 4) {
    const int j0 = max(max(i - WB, dlo - i), 0);
    const int j1 = min(min(i + WB, dhi1 - i), NN - 1);
    const int j = j0 + lane;
    if (j <= j1) {
      const int n = i + j;
      const int dd = n - dlo;
      const int l2 = i - lo_of(n);
      Rfull[(size_t)(i + 1) * RDIM + (j + 1)] = T[dd][l2];
    }
  }
}

// ---------------------------------------------------------------------------
// Fallback (ws too small): proven R3-style kernel (no workspace needed).
// ---------------------------------------------------------------------------
__global__ __launch_bounds__(256) void dtw_fb_kernel(const float* __restrict__ X,
                                                     const float* __restrict__ Y,
                                                     float* __restrict__ out) {
  __shared__ float xsT[DIMS][NN];
  __shared__ float ysT[DIMS][NN];
  __shared__ float x2s[NN];
  __shared__ float y2s[NN];
  __shared__ float ring[2][CHUNK][64];

  const int b = blockIdx.x;
  const int t = threadIdx.x;
  const float INF = __builtin_inff();

  {
    const float4* Xg = (const float4*)(X + (size_t)b * NN * DIMS);
    const float4* Yg = (const float4*)(Y + (size_t)b * NN * DIMS);
    for (int r = t; r < NN; r += 256) {
      float4 a0 = Xg[2 * r], a1 = Xg[2 * r + 1];
      xsT[0][r] = a0.x; xsT[1][r] = a0.y; xsT[2][r] = a0.z; xsT[3][r] = a0.w;
      xsT[4][r] = a1.x; xsT[5][r] = a1.y; xsT[6][r] = a1.z; xsT[7][r] = a1.w;
      x2s[r] = a0.x * a0.x + a0.y * a0.y + a0.z * a0.z + a0.w * a0.w +
               a1.x * a1.x + a1.y * a1.y + a1.z * a1.z + a1.w * a1.w;
      float4 c0 = Yg[2 * r], c1 = Yg[2 * r + 1];
      ysT[0][r] = c0.x; ysT[1][r] = c0.y; ysT[2][r] = c0.z; ysT[3][r] = c0.w;
      ysT[4][r] = c1.x; ysT[5][r] = c1.y; ysT[6][r] = c1.z; ysT[7][r] = c1.w;
      y2s[r] = c0.x * c0.x + c0.y * c0.y + c0.z * c0.z + c0.w * c0.w +
               c1.x * c1.x + c1.y * c1.y + c1.z * c1.z + c1.w * c1.w;
    }
  }
  __syncthreads();

  float* __restrict__ Rfull = out + BATCH + (size_t)b * RDIM * RDIM;
  if (t == 64) Rfull[0] = 0.0f;

  const int lane = t & 63;
  float r_d = INF, r_dm1 = INF;
  int lop = 0, lopp = 0;
  float Dcur = 0.0f;
  if (t < 64) {
    int i0 = min(lane, NN - 1);
    int j0 = max(0, min(0 - i0, NN - 1));
    float dot = xsT[0][i0] * ysT[0][j0] + xsT[1][i0] * ysT[1][j0] +
                xsT[2][i0] * ysT[2][j0] + xsT[3][i0] * ysT[3][j0] +
                xsT[4][i0] * ysT[4][j0] + xsT[5][i0] * ysT[5][j0] +
                xsT[6][i0] * ysT[6][j0] + xsT[7][i0] * ysT[7][j0];
    Dcur = (x2s[i0] + y2s[j0]) - 2.0f * dot;
  }

  for (int c = 0; c <= NCHUNK; ++c) {
    if (t < 64 && c < NCHUNK) {
      const int dlo = c * CHUNK;
      const int dhi = min(dlo + CHUNK, NDIAG);
      for (int n = dlo; n < dhi; ++n) {
        const int lon = lo_of(n), hin = hi_of(n);
        const int d1 = lon - lop;
        const int d2 = lon - lopp;
        const int sa = lane + d1;
        const int sb = sa - 1;
        const int sc = lane + d2 - 1;
        float va = __shfl(r_d, sa);   va = (sa < 64) ? va : INF;
        float vb = __shfl(r_d, sb);   vb = (sb >= 0) ? vb : INF;
        float vc = __shfl(r_dm1, sc); vc = (sc >= 0 && sc < 64) ? vc : INF;
        float rmin = fminf(fminf(vc, vb), va);
        if (n == 0) rmin = (lane == 0) ? 0.0f : INF;
        float r = Dcur + rmin;
        if (lane > hin - lon) r = INF;
        ring[c & 1][n - dlo][lane] = r;
        const int lon1 = lo_of(n + 1);
        int ii = min(lon1 + lane, NN - 1);
        int jj = n + 1 - ii; jj = max(0, min(jj, NN - 1));
        float dot = xsT[0][ii] * ysT[0][jj] + xsT[1][ii] * ysT[1][jj] +
                    xsT[2][ii] * ysT[2][jj] + xsT[3][ii] * ysT[3][jj] +
                    xsT[4][ii] * ysT[4][jj] + xsT[5][ii] * ysT[5][jj] +
                    xsT[6][ii] * ysT[6][jj] + xsT[7][ii] * ysT[7][jj];
        Dcur = (x2s[ii] + y2s[jj]) - 2.0f * dot;
        r_dm1 = r_d; r_d = r;
        lopp = lop; lop = lon;
      }
    } else if (t >= 64 && c >= 1) {
      const int dlo = (c - 1) * CHUNK;
      const int dhi = min(dlo + CHUNK, NDIAG);
      const int nslots = (dhi - dlo) * 64;
      const int buf = (c - 1) & 1;
      for (int s = t - 64; s < nslots; s += 192) {
        const int dd = s >> 6, l2 = s & 63;
        const int n = dlo + dd;
        const int lon = lo_of(n);
        const int i = lon + l2;
        if (i <= hi_of(n)) {
          Rfull[(size_t)(i + 1) * RDIM + (n - i + 1)] = ring[buf][dd][l2];
        }
      }
    }
    __syncthreads();
  }

  if (t == 0) out[b] = r_d;
}

extern "C" void kernel_launch(void* const* d_in, const int* in_sizes, int n_in,
                              void* d_out, int out_size, void* d_ws, size_t ws_size,
                              hipStream_t stream) {
  const float* X = (const float*)d_in[0];
  const float* Y = (const float*)d_in[1];
  float* out = (float*)d_out;

  const size_t nD = (size_t)BATCH * DPAD * 64;            // Dws floats (16.78 MB)
  const size_t nC = (size_t)BATCH * NGRP * 2 * 64;        // ckpt floats (2 MB)
  if (ws_size >= (nD + nC) * sizeof(float)) {
    float* Dws = (float*)d_ws;
    float* ckpt = (float*)d_ws + nD;
    dpre_kernel<<<(BATCH * DPAD) / 4, 256, 0, stream>>>(X, Y, Dws);
    dtw_chain_kernel<<<BATCH, 64, 0, stream>>>(Dws, ckpt, out);
    dtw_par_kernel<<<BATCH * NCHUNK, 256, 0, stream>>>(Dws, ckpt, out);
  } else {
    dtw_fb_kernel<<<BATCH, 256, 0, stream>>>(X, Y, out);
  }
}

// Round 21
// 40.252 us; speedup vs baseline: 2.2096x; 1.2051x over previous
//
#include <hip/hip_runtime.h>

#define BATCH 64
#define NN 512
#define DIMS 8
#define RDIM 514          // NN + 2
#define WB 51             // |i-j| <= 51  (0.1 * 511 = 51.1)
#define NDIAG (2 * NN - 1)            // 1023 real diagonals
#define DPAD 1024                     // padded diag count (diag 1023 = INF)
#define NG4 256                       // DPAD / 4 diag-groups of 4
#define CHUNK 64
#define NCHUNK 16                     // 16 * 64 = 1024 padded diagonals
#define GRP 16                        // checkpoint group size
#define NGRP 64                       // 1024 / 16

__device__ __forceinline__ constexpr int lo_of(int d) {
  int v = (d - (WB - 1)) >> 1;        // floor((d-50)/2)
  int w = d - (NN - 1);
  v = v > w ? v : w;
  return v > 0 ? v : 0;
}
__device__ __forceinline__ int hi_of(int d) {
  return min(min(d, NN - 1), (d + WB) >> 1);
}

// DPP wave shifts (VALU). bound_ctrl=false + old => shifted-in lanes get `old`.
// Semantics validated R4-R20 (kernels pass vs reference).
__device__ __forceinline__ float dpp_shr1(float x, float old) {  // lane i <- lane i-1
  return __int_as_float(__builtin_amdgcn_update_dpp(
      __float_as_int(old), __float_as_int(x), 0x138, 0xF, 0xF, false));
}
__device__ __forceinline__ float dpp_shl1(float x, float old) {  // lane i <- lane i+1
  return __int_as_float(__builtin_amdgcn_update_dpp(
      __float_as_int(old), __float_as_int(x), 0x130, 0xF, 0xF, false));
}

// D(i,j) (mirrors reference expansion (x2+y2) - 2*dot)
__device__ __forceinline__ float dval(const float* __restrict__ Xb,
                                      const float* __restrict__ Yb,
                                      int ic, int jc) {
  const float4* xp = (const float4*)(Xb + (size_t)ic * DIMS);
  const float4* yp = (const float4*)(Yb + (size_t)jc * DIMS);
  float4 xa = xp[0], xb2 = xp[1];
  float4 ya = yp[0], yb2 = yp[1];
  float x2 = xa.x * xa.x + xa.y * xa.y + xa.z * xa.z + xa.w * xa.w +
             xb2.x * xb2.x + xb2.y * xb2.y + xb2.z * xb2.z + xb2.w * xb2.w;
  float y2 = ya.x * ya.x + ya.y * ya.y + ya.z * ya.z + ya.w * ya.w +
             yb2.x * yb2.x + yb2.y * yb2.y + yb2.z * yb2.z + yb2.w * yb2.w;
  float dot = xa.x * ya.x + xa.y * ya.y + xa.z * ya.z + xa.w * ya.w +
              xb2.x * yb2.x + xb2.y * yb2.y + xb2.z * yb2.z + xb2.w * yb2.w;
  return (x2 + y2) - 2.0f * dot;
}

// ---------------------------------------------------------------------------
// Kernel 1: banded D, PACKED layout Dws4[(b*256 + ng)*64 + lane] = float4 of
// diagonals n = 4ng..4ng+3 at row lo_of(n)+lane. One float4 store per thread
// (wave writes 1 KB contiguous). XCD remap (R20): b = blockIdx.x & 63.
// ---------------------------------------------------------------------------
__global__ __launch_bounds__(256) void dpre_kernel(const float* __restrict__ X,
                                                   const float* __restrict__ Y,
                                                   float4* __restrict__ Dws4) {
  const int b = blockIdx.x & 63;                           // batch == XCD class
  const int ng = (blockIdx.x >> 6) * 4 + (threadIdx.x >> 6);  // [0, 256)
  const int lane = threadIdx.x & 63;
  const float INF = __builtin_inff();
  const float* __restrict__ Xb = X + (size_t)b * NN * DIMS;
  const float* __restrict__ Yb = Y + (size_t)b * NN * DIMS;
  float o[4];
#pragma unroll
  for (int k = 0; k < 4; ++k) {
    const int n = 4 * ng + k;
    const int lon = lo_of(n);
    const int i = lon + lane;
    const bool valid = (i <= hi_of(n)) && (n < NDIAG);
    const int ic = min(i, NN - 1);
    const int jc = min(max(n - ic, 0), NN - 1);
    float D = dval(Xb, Yb, ic, jc);
    o[k] = valid ? D : INF;
  }
  Dws4[((size_t)b * NG4 + ng) * 64 + lane] = make_float4(o[0], o[1], o[2], o[3]);
}

// ---- shared recurrence step macros (R10-R20 proven semantics) --------------
#define BODY_STEP(qm, n)                                                    \
      const int lon = lo_of(n);                                             \
      const int d1 = lon - lo_of((n) - 1);                                  \
      const int d2 = lon - lo_of((n) - 2);                                  \
      float s_shl = dpp_shl1(r_d, INF);                                     \
      float s_shr = dpp_shr1(r_d, INF);                                     \
      float tt = d1 ? s_shl : s_shr;                                        \
      float vc = (d2 == 0) ? shm_shr : ((d2 == 1) ? r_dm1 : shm_shl);       \
      float r = (qm) + fminf(fminf(r_d, tt), vc);                           \
      r_dm1 = r_d; shm_shl = s_shl; shm_shr = s_shr; r_d = r;

// steady body (n in [52,972]): d2==1 -> vc=r_dm1; d1 = (n even) = (m even)
#define STEADY_STEP(qm, m)                                                  \
      float tt = ((m & 1) == 0) ? dpp_shl1(r_d, INF) : dpp_shr1(r_d, INF);  \
      float r = (qm) + fminf(fminf(r_d, tt), r_dm1);                        \
      r_dm1 = r_d; r_d = r;

// ---------------------------------------------------------------------------
// Kernel 2 (pass 1): serial chain, 1 wave/batch, launch_bounds(64,1), triple-
// buffered D prefetch. CHANGE (R21): chunk loads are 16 dwordx4 instead of 64
// scalar — 4x fewer vmcnt slots (6-bit counter, max 63 outstanding), so the
// 2-chunk-ahead prefetch actually fits in flight and HBM latency stays hidden
// even on cold misses. LDS checkpoints (R19) every 16 diagonals (R17).
// ---------------------------------------------------------------------------
__global__ __launch_bounds__(64, 1) void dtw_chain_kernel(const float4* __restrict__ Dws4,
                                                          float* __restrict__ ckpt,
                                                          float* __restrict__ out) {
  __shared__ float ckls[NGRP * 2 * 64];   // 32 KB checkpoint staging
  const int b = blockIdx.x;
  const int lane = threadIdx.x;
  const float INF = __builtin_inff();
  const float4* __restrict__ Db4 = Dws4 + (size_t)b * NG4 * 64 + lane;

  float qA[CHUNK], qB[CHUNK], qC[CHUNK];

#define LOAD_CHUNK(q, cRt)                                                  \
  { _Pragma("unroll")                                                       \
    for (int mg = 0; mg < 16; ++mg) {                                       \
      float4 v = Db4[(size_t)((cRt) * 16 + mg) * 64];                       \
      (q)[4 * mg + 0] = v.x; (q)[4 * mg + 1] = v.y;                         \
      (q)[4 * mg + 2] = v.z; (q)[4 * mg + 3] = v.w;                         \
    } }

#define CKPT16(g)                                                           \
  { ckls[((g) * 2 + 0) * 64 + lane] = r_d;                                  \
    ckls[((g) * 2 + 1) * 64 + lane] = r_dm1; }

  float r_d = INF, r_dm1 = INF, shm_shl = INF;
  float shm_shr = (lane == 0) ? 0.0f : INF;   // n=0 (d2==0) seed: rmin=0@lane0

  LOAD_CHUNK(qA, 0)
  LOAD_CHUNK(qB, 1)
  LOAD_CHUNK(qC, 2)
  {
#pragma unroll
    for (int m = 0; m < CHUNK; ++m) {
      if ((m & 15) == 0) { CKPT16(m >> 4) }
      BODY_STEP(qA[m], 0 + m)
    }
  }
  LOAD_CHUNK(qA, 3)
#pragma unroll 1
  for (int c = 1; c <= 10; c += 3) {        // chunks 1..12 (all steady)
    {
#pragma unroll
      for (int m = 0; m < CHUNK; ++m) {
        if ((m & 15) == 0) { CKPT16(c * 4 + (m >> 4)) }
        STEADY_STEP(qB[m], m)
      }
    }
    LOAD_CHUNK(qB, c + 3)
    {
#pragma unroll
      for (int m = 0; m < CHUNK; ++m) {
        if ((m & 15) == 0) { CKPT16((c + 1) * 4 + (m >> 4)) }
        STEADY_STEP(qC[m], m)
      }
    }
    LOAD_CHUNK(qC, c + 4)
    {
#pragma unroll
      for (int m = 0; m < CHUNK; ++m) {
        if ((m & 15) == 0) { CKPT16((c + 2) * 4 + (m >> 4)) }
        STEADY_STEP(qA[m], m)
      }
    }
    LOAD_CHUNK(qA, c + 5)
  }
  {
#pragma unroll
    for (int m = 0; m < CHUNK; ++m) {
      if ((m & 15) == 0) { CKPT16(13 * 4 + (m >> 4)) }
      STEADY_STEP(qB[m], m)
    }
  }
  {
#pragma unroll
    for (int m = 0; m < CHUNK; ++m) {
      if ((m & 15) == 0) { CKPT16(14 * 4 + (m >> 4)) }
      STEADY_STEP(qC[m], m)
    }
  }
  {
#pragma unroll
    for (int m = 0; m < CHUNK; ++m) {
      if ((m & 15) == 0) { CKPT16(15 * 4 + (m >> 4)) }
      BODY_STEP(qA[m], 960 + m)
    }
  }

  if (lane == 0) out[b] = r_dm1;    // lane0 of diag 1022 = R[511][511]

  // ---- flush LDS ckpt -> global (coalesced float4) ----
  {
    const float4* s4 = (const float4*)ckls;
    float4* d4 = (float4*)(ckpt + (size_t)b * (NGRP * 2) * 64);
    for (int k = lane; k < NGRP * 2 * 16; k += 64) d4[k] = s4[k];
  }
#undef LOAD_CHUNK
#undef CKPT16
}

// ---------------------------------------------------------------------------
// Kernel 3 (pass 2): ALL-WAVE-PARALLEL recompute + fused transpose (R17).
// R21: q loaded as 4 float4s (coalesced 1 KB/wave). XCD remap (R20).
// ---------------------------------------------------------------------------
__global__ __launch_bounds__(256) void dtw_par_kernel(const float4* __restrict__ Dws4,
                                                      const float* __restrict__ ckpt,
                                                      float* __restrict__ out) {
  __shared__ float T[CHUNK][65];
  const int b = blockIdx.x & 63;
  const int cc = blockIdx.x >> 6;
  const int t = threadIdx.x;
  const int wave = t >> 6, lane = t & 63;
  const float INF = __builtin_inff();
  const int dlo = cc * CHUNK;

  float* __restrict__ Rfull = out + BATCH + (size_t)b * RDIM * RDIM;
  if (cc == 0 && t == 0) Rfull[0] = 0.0f;   // R[b][0][0] = 0

  // ---- parallel recompute: group g = cc*4 + wave, diags n0..n0+15 ----
  {
    const int g = cc * 4 + wave;
    const int n0 = g * GRP;
    const float4* __restrict__ Db4 = Dws4 + ((size_t)b * NG4 + g * 4) * 64 + lane;
    float q[GRP];
#pragma unroll
    for (int mg = 0; mg < 4; ++mg) {
      float4 v = Db4[(size_t)mg * 64];
      q[4 * mg + 0] = v.x; q[4 * mg + 1] = v.y;
      q[4 * mg + 2] = v.z; q[4 * mg + 3] = v.w;
    }

    const float* __restrict__ ckb =
        ckpt + ((size_t)b * (NGRP * 2) + g * 2) * 64 + lane;
    float r_d = ckb[0];
    float r_dm1 = ckb[64];
    // group-entry invariant: shm_* == shifts of r_dm1 (group 0 re-seeds)
    float shm_shl = dpp_shl1(r_dm1, INF);
    float shm_shr = dpp_shr1(r_dm1, INF);
    if (g == 0) shm_shr = (lane == 0) ? 0.0f : INF;   // n=0 seed

    int lop = lo_of(n0 - 1), lopp = lo_of(n0 - 2);
#pragma unroll
    for (int m = 0; m < GRP; ++m) {
      const int n = n0 + m;
      const int lon = lo_of(n);
      const int d1 = lon - lop;
      const int d2 = lon - lopp;
      float s_shl = dpp_shl1(r_d, INF);
      float s_shr = dpp_shr1(r_d, INF);
      float tt = d1 ? s_shl : s_shr;
      float vc = (d2 == 0) ? shm_shr : ((d2 == 1) ? r_dm1 : shm_shl);
      float r = q[m] + fminf(fminf(r_d, tt), vc);
      T[wave * GRP + m][lane] = r;
      r_dm1 = r_d; shm_shl = s_shl; shm_shr = s_shr; r_d = r;
      lopp = lop; lop = lon;
    }
  }
  __syncthreads();

  // ---- row-major band segments (proven R6-R20 tail) ----
  const int dhi1 = min(dlo + CHUNK - 1, NDIAG - 1);
  const int rlo = lo_of(dlo);
  const int rhi = hi_of(dhi1);
  for (int i = rlo + wave; i <= rhi; i += 4) {
    const int j0 = max(max(i - WB, dlo - i), 0);
    const int j1 = min(min(i + WB, dhi1 - i), NN - 1);
    const int j = j0 + lane;
    if (j <= j1) {
      const int n = i + j;
      const int dd = n - dlo;
      const int l2 = i - lo_of(n);
      Rfull[(size_t)(i + 1) * RDIM + (j + 1)] = T[dd][l2];
    }
  }
}

// ---------------------------------------------------------------------------
// Fallback (ws too small): proven R3-style kernel (no workspace needed).
// ---------------------------------------------------------------------------
__global__ __launch_bounds__(256) void dtw_fb_kernel(const float* __restrict__ X,
                                                     const float* __restrict__ Y,
                                                     float* __restrict__ out) {
  __shared__ float xsT[DIMS][NN];
  __shared__ float ysT[DIMS][NN];
  __shared__ float x2s[NN];
  __shared__ float y2s[NN];
  __shared__ float ring[2][CHUNK][64];

  const int b = blockIdx.x;
  const int t = threadIdx.x;
  const float INF = __builtin_inff();

  {
    const float4* Xg = (const float4*)(X + (size_t)b * NN * DIMS);
    const float4* Yg = (const float4*)(Y + (size_t)b * NN * DIMS);
    for (int r = t; r < NN; r += 256) {
      float4 a0 = Xg[2 * r], a1 = Xg[2 * r + 1];
      xsT[0][r] = a0.x; xsT[1][r] = a0.y; xsT[2][r] = a0.z; xsT[3][r] = a0.w;
      xsT[4][r] = a1.x; xsT[5][r] = a1.y; xsT[6][r] = a1.z; xsT[7][r] = a1.w;
      x2s[r] = a0.x * a0.x + a0.y * a0.y + a0.z * a0.z + a0.w * a0.w +
               a1.x * a1.x + a1.y * a1.y + a1.z * a1.z + a1.w * a1.w;
      float4 c0 = Yg[2 * r], c1 = Yg[2 * r + 1];
      ysT[0][r] = c0.x; ysT[1][r] = c0.y; ysT[2][r] = c0.z; ysT[3][r] = c0.w;
      ysT[4][r] = c1.x; ysT[5][r] = c1.y; ysT[6][r] = c1.z; ysT[7][r] = c1.w;
      y2s[r] = c0.x * c0.x + c0.y * c0.y + c0.z * c0.z + c0.w * c0.w +
               c1.x * c1.x + c1.y * c1.y + c1.z * c1.z + c1.w * c1.w;
    }
  }
  __syncthreads();

  float* __restrict__ Rfull = out + BATCH + (size_t)b * RDIM * RDIM;
  if (t == 64) Rfull[0] = 0.0f;

  const int lane = t & 63;
  float r_d = INF, r_dm1 = INF;
  int lop = 0, lopp = 0;
  float Dcur = 0.0f;
  if (t < 64) {
    int i0 = min(lane, NN - 1);
    int j0 = max(0, min(0 - i0, NN - 1));
    float dot = xsT[0][i0] * ysT[0][j0] + xsT[1][i0] * ysT[1][j0] +
                xsT[2][i0] * ysT[2][j0] + xsT[3][i0] * ysT[3][j0] +
                xsT[4][i0] * ysT[4][j0] + xsT[5][i0] * ysT[5][j0] +
                xsT[6][i0] * ysT[6][j0] + xsT[7][i0] * ysT[7][j0];
    Dcur = (x2s[i0] + y2s[j0]) - 2.0f * dot;
  }

  for (int c = 0; c <= NCHUNK; ++c) {
    if (t < 64 && c < NCHUNK) {
      const int dlo = c * CHUNK;
      const int dhi = min(dlo + CHUNK, NDIAG);
      for (int n = dlo; n < dhi; ++n) {
        const int lon = lo_of(n), hin = hi_of(n);
        const int d1 = lon - lop;
        const int d2 = lon - lopp;
        const int sa = lane + d1;
        const int sb = sa - 1;
        const int sc = lane + d2 - 1;
        float va = __shfl(r_d, sa);   va = (sa < 64) ? va : INF;
        float vb = __shfl(r_d, sb);   vb = (sb >= 0) ? vb : INF;
        float vc = __shfl(r_dm1, sc); vc = (sc >= 0 && sc < 64) ? vc : INF;
        float rmin = fminf(fminf(vc, vb), va);
        if (n == 0) rmin = (lane == 0) ? 0.0f : INF;
        float r = Dcur + rmin;
        if (lane > hin - lon) r = INF;
        ring[c & 1][n - dlo][lane] = r;
        const int lon1 = lo_of(n + 1);
        int ii = min(lon1 + lane, NN - 1);
        int jj = n + 1 - ii; jj = max(0, min(jj, NN - 1));
        float dot = xsT[0][ii] * ysT[0][jj] + xsT[1][ii] * ysT[1][jj] +
                    xsT[2][ii] * ysT[2][jj] + xsT[3][ii] * ysT[3][jj] +
                    xsT[4][ii] * ysT[4][jj] + xsT[5][ii] * ysT[5][jj] +
                    xsT[6][ii] * ysT[6][jj] + xsT[7][ii] * ysT[7][jj];
        Dcur = (x2s[ii] + y2s[jj]) - 2.0f * dot;
        r_dm1 = r_d; r_d = r;
        lopp = lop; lop = lon;
      }
    } else if (t >= 64 && c >= 1) {
      const int dlo = (c - 1) * CHUNK;
      const int dhi = min(dlo + CHUNK, NDIAG);
      const int nslots = (dhi - dlo) * 64;
      const int buf = (c - 1) & 1;
      for (int s = t - 64; s < nslots; s += 192) {
        const int dd = s >> 6, l2 = s & 63;
        const int n = dlo + dd;
        const int lon = lo_of(n);
        const int i = lon + l2;
        if (i <= hi_of(n)) {
          Rfull[(size_t)(i + 1) * RDIM + (n - i + 1)] = ring[buf][dd][l2];
        }
      }
    }
    __syncthreads();
  }

  if (t == 0) out[b] = r_d;
}

extern "C" void kernel_launch(void* const* d_in, const int* in_sizes, int n_in,
                              void* d_out, int out_size, void* d_ws, size_t ws_size,
                              hipStream_t stream) {
  const float* X = (const float*)d_in[0];
  const float* Y = (const float*)d_in[1];
  float* out = (float*)d_out;

  const size_t nD = (size_t)BATCH * DPAD * 64;            // Dws floats (16.78 MB)
  const size_t nC = (size_t)BATCH * NGRP * 2 * 64;        // ckpt floats (2 MB)
  if (ws_size >= (nD + nC) * sizeof(float)) {
    float4* Dws4 = (float4*)d_ws;
    float* ckpt = (float*)d_ws + nD;
    dpre_kernel<<<(BATCH * NG4) / 4, 256, 0, stream>>>(X, Y, Dws4);
    dtw_chain_kernel<<<BATCH, 64, 0, stream>>>(Dws4, ckpt, out);
    dtw_par_kernel<<<BATCH * NCHUNK, 256, 0, stream>>>(Dws4, ckpt, out);
  } else {
    dtw_fb_kernel<<<BATCH, 256, 0, stream>>>(X, Y, out);
  }
}